// Round 9
// baseline (222.350 us; speedup 1.0000x reference)
//
#include <hip/hip_runtime.h>
#include <hip/hip_bf16.h>

#define BLOCK   512     // 8 waves; wave w owns channels w*16..w*16+15, all 4 gates
#define NSAMP   16
#define HDIM    128
#define DDIM    16
#define NOBJ    6
#define NSLOT   14

typedef __attribute__((ext_vector_type(8))) short bf16x8;
typedef __attribute__((ext_vector_type(4))) float f32x4;

constexpr int pc6(int m)  { int c = 0; for (int i = 0; i < 6; ++i) c += (m >> i) & 1; return c; }
constexpr int msb6(int m) { int b = -1; for (int i = 0; i < 6; ++i) if (m & (1 << i)) b = i; return b; }

// ---- Grouped plan (verified R4): children grouped by PARENT so W_hh*h_P (zh)
// is computed ONCE per parent; 14-slot pool with recycle barriers.
struct GChild { int jo, sl; bool bar; };
struct Plan3 {
    int    gps [32];
    int    gbeg[33];
    GChild ch  [63];
    int    lvlG[8];
    bool   ok;
};
constexpr Plan3 make_plan3() {
    Plan3 P{};
    P.ok = true;
    int  slotOf[64] = {};
    bool busy[NSLOT] = {};
    int  pendingFree[NSLOT] = {};
    int  npend = 0;
    int  g = 0, cidx = 0;
    for (int d = 1; d <= 6; ++d) {
        P.lvlG[d] = g;
        for (int Pm = 0; Pm < 64; ++Pm) {
            if (pc6(Pm) != d - 1) continue;
            if (Pm != 0 && msb6(Pm) == 5) continue;
            P.gps[g]  = (Pm == 0) ? -1 : slotOf[Pm];
            P.gbeg[g] = cidx;
            if (Pm != 0) pendingFree[npend++] = slotOf[Pm];
            const int j0 = (Pm == 0) ? 0 : msb6(Pm) + 1;
            for (int j = j0; j <= 5; ++j) {
                const int M = Pm | (1 << j);
                P.ch[cidx].jo  = j;
                P.ch[cidx].bar = false;
                int sl = -1;
                if (j < 5) {
                    int fs = -1;
                    for (int s = 0; s < NSLOT; ++s) if (!busy[s]) { fs = s; break; }
                    if (fs < 0) {
                        P.ch[cidx].bar = true;
                        if (npend == 0) P.ok = false;
                        for (int i = 0; i < npend; ++i) busy[pendingFree[i]] = false;
                        npend = 0;
                        for (int s = 0; s < NSLOT; ++s) if (!busy[s]) { fs = s; break; }
                        if (fs < 0) P.ok = false;
                    }
                    if (fs >= 0) { busy[fs] = true; slotOf[M] = fs; sl = fs; }
                }
                P.ch[cidx].sl = sl;
                ++cidx;
            }
            ++g;
        }
        for (int i = 0; i < npend; ++i) busy[pendingFree[i]] = false;
        npend = 0;
    }
    P.lvlG[7] = g;
    P.gbeg[g] = cidx;
    if (g != 32 || cidx != 63) P.ok = false;
    return P;
}
constexpr Plan3 PL3 = make_plan3();
static_assert(PL3.ok, "plan allocation failed");
static_assert(PL3.lvlG[7] == 32, "32 groups expected");
static_assert(PL3.gbeg[32] == 63, "63 children expected");

// ---- Runtime (ROLLED) plan tables.  R9 theory: the fully-unrolled 63-node
// body (~40-50 KB straight-line code) is INSTRUCTION-FETCH bound — L1I (~32KB)
// streams with no reuse; this uniquely explains R7(2 rounds x C) == R8(1 round
// x 2C) and the R4-R8 136-141us invariance across instruction mixes.  Rolled
// loop body ~1 KB -> L1I-resident.  Tables are constant-initialized device
// memory; #pragma unroll 1 stops re-unrolling.
struct PlanRT {
    int           gps [32];
    int           gbeg[33];
    unsigned char gbar[32];     // barrier before group (level start)
    unsigned char cjo [63];
    signed char   csl [63];
    unsigned char cbar[63];     // recycle barrier before child
};
constexpr PlanRT make_rt() {
    PlanRT R{};
    for (int i = 0; i < 32; ++i) { R.gps[i] = PL3.gps[i]; R.gbar[i] = 0; }
    for (int i = 0; i < 33; ++i) R.gbeg[i] = PL3.gbeg[i];
    for (int d = 1; d <= 6; ++d) R.gbar[PL3.lvlG[d]] = 1;
    for (int i = 0; i < 63; ++i) {
        R.cjo[i]  = (unsigned char)PL3.ch[i].jo;
        R.csl[i]  = (signed char)PL3.ch[i].sl;
        R.cbar[i] = PL3.ch[i].bar ? 1 : 0;
    }
    return R;
}
__device__ const PlanRT DPL = make_rt();

#define LOG2E   1.44269504f
#define TWOL2E  2.88539008f
#define SLOT_SH 2048            // shorts per slot (4 KB), h and c pools

__device__ __forceinline__ unsigned short f2bf(float x) {
    union { float f; unsigned int u; } a; a.f = x;
    unsigned int r = (a.u + 0x7FFFu + ((a.u >> 16) & 1u)) >> 16;
    return (unsigned short)r;
}
__device__ __forceinline__ unsigned pk2(float a, float b) {
    union { __hip_bfloat162 h; unsigned u; } z;
    z.h = __float22bfloat162_rn(float2{a, b});
    return z.u;
}
__device__ __forceinline__ float bflo(unsigned p) {
    union { unsigned u; float f; } a; a.u = p << 16; return a.f;
}
__device__ __forceinline__ float bfhi(unsigned p) {
    union { unsigned u; float f; } a; a.u = p & 0xFFFF0000u; return a.f;
}

// h pool: hs[((slot*16 + kslot)*NSAMP + n)*8 + j]  (R0-verified layout)
// c pool: csb[t*4 + slot*2048]  lane-linear uint2 (R0-verified, conflict-free)

__global__ __launch_bounds__(BLOCK)
__attribute__((amdgpu_waves_per_eu(2, 4)))   // attested no-scratch envelope
void subset_lstm_skew_kernel(
    const float* __restrict__ x_input,
    const float* __restrict__ W_ih,
    const float* __restrict__ W_hh,
    const float* __restrict__ b_ih,
    const float* __restrict__ b_hh,
    const float* __restrict__ fc1_W,
    const float* __restrict__ fc1_b,
    const float* __restrict__ fc2_W,
    const float* __restrict__ fc2_b,
    float* __restrict__ out)
{
    __shared__ __align__(16) unsigned short hs [NSLOT * SLOT_SH];       // 56 KB
    __shared__ __align__(16) unsigned short csb[NSLOT * SLOT_SH];       // 56 KB
    __shared__ __align__(16) unsigned short xb[NOBJ * 4 * NSAMP * 8];   // 6 KB
    float* s_maxh  = (float*)hs;                 // 8 KB  (post-LSTM alias)
    float* s_fc1   = (float*)(hs + 4096);        // 16 KB (post-LSTM alias)
    float* s_logit = (float*)xb;

    const int t      = threadIdx.x;
    const int w      = t >> 6;
    const int lane   = t & 63;
    const int quad   = lane >> 4;
    const int m16    = lane & 15;
    const int s_base = blockIdx.x * NSAMP;

    // ---- x B-chunks: xb[obj][quad'][n][j]; quad2 j0 = 1.0 (bias lane), quad3 zero ----
    for (int idx = t; idx < NOBJ * 4 * NSAMP * 8; idx += BLOCK) {
        const int j = idx & 7, n = (idx >> 3) & 15, q = (idx >> 7) & 3, obj = idx >> 9;
        float v;
        if (q < 2) v = x_input[(s_base + n) * (NOBJ * DDIM) + obj * DDIM + q * 8 + j];
        else       v = (q == 2 && j == 0) ? 1.0f : 0.0f;
        xb[idx] = f2bf(v);
    }

    // ---- persistent A-frags wf[gate][chunk], PRE-SCALED (verified R8-R13) ----
    bf16x8 wf[4][5];
    #pragma unroll
    for (int g = 0; g < 4; ++g) {
        const float sc = (g == 2) ? TWOL2E : -LOG2E;
        const int grow = g * HDIM + w * 16 + m16;
        const float* whr = W_hh + grow * HDIM;
        const float* wir = W_ih + grow * DDIM;
        #pragma unroll
        for (int q = 0; q < 4; ++q) {
            union { unsigned short u[8]; bf16x8 v; } pk;
            #pragma unroll
            for (int j = 0; j < 8; ++j)
                pk.u[j] = f2bf(sc * whr[q * 32 + quad * 8 + j]);
            wf[g][q] = pk.v;
        }
        {
            union { unsigned short u[8]; bf16x8 v; } pk;
            #pragma unroll
            for (int j = 0; j < 8; ++j) {
                float v = 0.0f;
                if (quad < 2) v = sc * wir[quad * 8 + j];
                else if (quad == 2 && j == 0) v = sc * (b_ih[grow] + b_hh[grow]);
                pk.u[j] = f2bf(v);
            }
            wf[g][4] = pk.v;
        }
    }

    float mh[4] = {-1e30f, -1e30f, -1e30f, -1e30f};
    const int kslot = w * 2 + (quad >> 1);
    unsigned short* const c_lane = &csb[t * 4];

    // ---- main loop: ROLLED over groups and children ----
    #pragma unroll 1
    for (int gi = 0; gi < 32; ++gi) {
        if (DPL.gbar[gi]) __syncthreads();
        const int ps = DPL.gps[gi];
        f32x4 zh[4];
        float cp4[4];
        #pragma unroll
        for (int g2 = 0; g2 < 4; ++g2) zh[g2] = f32x4{0.f, 0.f, 0.f, 0.f};
        if (ps >= 0) {
            const uint2 cpk = *(const uint2*)(c_lane + ps * SLOT_SH);
            cp4[0] = bflo(cpk.x); cp4[1] = bfhi(cpk.x);
            cp4[2] = bflo(cpk.y); cp4[3] = bfhi(cpk.y);
            #pragma unroll
            for (int q = 0; q < 4; ++q) {
                const bf16x8 bh = *(const bf16x8*)
                    &hs[((ps * 16 + q * 4 + quad) * NSAMP + m16) * 8];
                #pragma unroll
                for (int g2 = 0; g2 < 4; ++g2)
                    zh[g2] = __builtin_amdgcn_mfma_f32_16x16x32_bf16(
                        wf[g2][q], bh, zh[g2], 0, 0, 0);
            }
        } else {
            #pragma unroll
            for (int r = 0; r < 4; ++r) cp4[r] = 0.0f;
        }
        const int cB = DPL.gbeg[gi];
        const int cE = DPL.gbeg[gi + 1];
        #pragma unroll 1
        for (int ci = cB; ci < cE; ++ci) {
            if (DPL.cbar[ci]) __syncthreads();
            const int jo = DPL.cjo[ci];
            const int sl = DPL.csl[ci];
            const bf16x8 bfx = *(const bf16x8*)
                &xb[((jo * 4 + quad) * NSAMP + m16) * 8];
            f32x4 acc[4];
            #pragma unroll
            for (int g2 = 0; g2 < 4; ++g2)
                acc[g2] = __builtin_amdgcn_mfma_f32_16x16x32_bf16(
                    wf[g2][4], bfx, zh[g2], 0, 0, 0);
            float cn4[4], hn4[4];
            #pragma unroll
            for (int r = 0; r < 4; ++r) {
                const float u  = 1.0f + __builtin_amdgcn_exp2f(acc[0][r]);
                const float q  = 1.0f + __builtin_amdgcn_exp2f(acc[1][r]);
                const float v  = 1.0f + __builtin_amdgcn_exp2f(acc[2][r]);
                const float qo = 1.0f + __builtin_amdgcn_exp2f(acc[3][r]);
                const float uv  = u * v;
                const float num = fmaf(q, v - 2.0f, cp4[r] * uv);
                const float cn  = num * __builtin_amdgcn_rcpf(q * uv);
                const float wt  = 1.0f + __builtin_amdgcn_exp2f(TWOL2E * cn);
                const float h   = (wt - 2.0f) * __builtin_amdgcn_rcpf(qo * wt);
                cn4[r] = cn; hn4[r] = h;
                mh[r] = fmaxf(mh[r], h);
            }
            if (sl >= 0) {
                uint2 cw; cw.x = pk2(cn4[0], cn4[1]); cw.y = pk2(cn4[2], cn4[3]);
                *(uint2*)(c_lane + sl * SLOT_SH) = cw;
                uint2 hw; hw.x = pk2(hn4[0], hn4[1]); hw.y = pk2(hn4[2], hn4[3]);
                *(uint2*)&hs[((sl * 16 + kslot) * NSAMP + m16) * 8 + (quad & 1) * 4] = hw;
            }
        }
    }

    __syncthreads();   // pools dead; reuse hs for epilogue
    {
        float4 v; v.x = mh[0]; v.y = mh[1]; v.z = mh[2]; v.w = mh[3];
        *(float4*)&s_maxh[m16 * HDIM + w * 16 + quad * 4] = v;
    }
    __syncthreads();

    // ---- FC1: f = t&255, sample half t>>8 (8 samples each) ----
    {
        const int f  = t & 255;
        const int sh = t >> 8;
        float a1[8];
        #pragma unroll
        for (int s = 0; s < 8; ++s) a1[s] = fc1_b[f];
        for (int k4 = 0; k4 < HDIM / 4; ++k4) {
            const float4 wv = *(const float4*)&fc1_W[f * HDIM + k4 * 4];
            #pragma unroll
            for (int s = 0; s < 8; ++s) {
                const float4 h4 = *(const float4*)&s_maxh[(sh * 8 + s) * HDIM + k4 * 4];
                a1[s] += wv.x * h4.x + wv.y * h4.y + wv.z * h4.z + wv.w * h4.w;
            }
        }
        #pragma unroll
        for (int s = 0; s < 8; ++s)
            s_fc1[(sh * 8 + s) * 256 + f] = fmaxf(a1[s], 0.0f);
    }
    __syncthreads();

    if (t < NSAMP * 10) {
        const int s = t / 10, a = t % 10;
        float acc2 = fc2_b[a];
        for (int f4 = 0; f4 < 256 / 4; ++f4) {
            const float4 wv = *(const float4*)&fc2_W[a * 256 + f4 * 4];
            const float4 v  = *(const float4*)&s_fc1[s * 256 + f4 * 4];
            acc2 += wv.x * v.x + wv.y * v.y + wv.z * v.z + wv.w * v.w;
        }
        s_logit[s * 10 + a] = acc2;
    }
    __syncthreads();

    if (t < NSAMP) {
        float m = -1e30f;
        #pragma unroll
        for (int a = 0; a < 10; ++a) m = fmaxf(m, s_logit[t * 10 + a]);
        float sum = 0.0f;
        #pragma unroll
        for (int a = 0; a < 10; ++a) sum += __expf(s_logit[t * 10 + a] - m);
        const float lse = m + __logf(sum);
        #pragma unroll
        for (int a = 0; a < 10; ++a)
            out[(s_base + t) * 10 + a] = s_logit[t * 10 + a] - lse;
    }
}

extern "C" void kernel_launch(void* const* d_in, const int* in_sizes, int n_in,
                              void* d_out, int out_size, void* d_ws, size_t ws_size,
                              hipStream_t stream)
{
    (void)d_ws; (void)ws_size; (void)n_in; (void)out_size;

    const float* x   = (const float*)d_in[0];
    const float* Wih = (const float*)d_in[1];
    const float* Whh = (const float*)d_in[2];
    const float* bih = (const float*)d_in[3];
    const float* bhh = (const float*)d_in[4];
    const float* f1w = (const float*)d_in[5];
    const float* f1b = (const float*)d_in[6];
    const float* f2w = (const float*)d_in[7];
    const float* f2b = (const float*)d_in[8];

    const int mb = in_sizes[0] / (NOBJ * DDIM);   // 8192
    dim3 grid(mb / NSAMP), block(BLOCK);
    subset_lstm_skew_kernel<<<grid, block, 0, stream>>>(
        x, Wih, Whh, bih, bhh, f1w, f1b, f2w, f2b, (float*)d_out);
}

// Round 10
// 212.491 us; speedup vs baseline: 1.0464x; 1.0464x over previous
//
#include <hip/hip_runtime.h>
#include <hip/hip_bf16.h>

#define BLOCK   512     // 8 waves; wave w owns channels w*16..w*16+15, all 4 gates
#define NSAMP   16
#define HDIM    128
#define DDIM    16
#define NOBJ    6
#define NSLOT   14

typedef __attribute__((ext_vector_type(8))) short bf16x8;
typedef __attribute__((ext_vector_type(4))) float f32x4;

constexpr int pc6(int m)  { int c = 0; for (int i = 0; i < 6; ++i) c += (m >> i) & 1; return c; }
constexpr int msb6(int m) { int b = -1; for (int i = 0; i < 6; ++i) if (m & (1 << i)) b = i; return b; }

// ---- Grouped plan (verified R4): children grouped by PARENT so W_hh*h_P (zh)
// is computed ONCE per parent; 14-slot pool with recycle barriers.
struct GChild { int jo, sl; bool bar; };
struct Plan3 {
    int    gps [32];
    int    gbeg[33];
    GChild ch  [63];
    int    lvlG[8];
    bool   ok;
};
constexpr Plan3 make_plan3() {
    Plan3 P{};
    P.ok = true;
    int  slotOf[64] = {};
    bool busy[NSLOT] = {};
    int  pendingFree[NSLOT] = {};
    int  npend = 0;
    int  g = 0, cidx = 0;
    for (int d = 1; d <= 6; ++d) {
        P.lvlG[d] = g;
        for (int Pm = 0; Pm < 64; ++Pm) {
            if (pc6(Pm) != d - 1) continue;
            if (Pm != 0 && msb6(Pm) == 5) continue;
            P.gps[g]  = (Pm == 0) ? -1 : slotOf[Pm];
            P.gbeg[g] = cidx;
            if (Pm != 0) pendingFree[npend++] = slotOf[Pm];
            const int j0 = (Pm == 0) ? 0 : msb6(Pm) + 1;
            for (int j = j0; j <= 5; ++j) {
                const int M = Pm | (1 << j);
                P.ch[cidx].jo  = j;
                P.ch[cidx].bar = false;
                int sl = -1;
                if (j < 5) {
                    int fs = -1;
                    for (int s = 0; s < NSLOT; ++s) if (!busy[s]) { fs = s; break; }
                    if (fs < 0) {
                        P.ch[cidx].bar = true;
                        if (npend == 0) P.ok = false;
                        for (int i = 0; i < npend; ++i) busy[pendingFree[i]] = false;
                        npend = 0;
                        for (int s = 0; s < NSLOT; ++s) if (!busy[s]) { fs = s; break; }
                        if (fs < 0) P.ok = false;
                    }
                    if (fs >= 0) { busy[fs] = true; slotOf[M] = fs; sl = fs; }
                }
                P.ch[cidx].sl = sl;
                ++cidx;
            }
            ++g;
        }
        for (int i = 0; i < npend; ++i) busy[pendingFree[i]] = false;
        npend = 0;
    }
    P.lvlG[7] = g;
    P.gbeg[g] = cidx;
    if (g != 32 || cidx != 63) P.ok = false;
    return P;
}
constexpr Plan3 PL3 = make_plan3();
static_assert(PL3.ok, "plan allocation failed");
static_assert(PL3.lvlG[7] == 32, "32 groups expected");
static_assert(PL3.gbeg[32] == 63, "63 children expected");

// ---- R10: FLAT packed descriptor stream, one u32 per child.
//   bits 0-2  : jo
//   bits 3-7  : sl   (31 = none/leaf)
//   bit  8    : recycle barrier before this child
//   bit  9    : new group (run zh chain with ps)
//   bits 10-14: ps   (31 = root/none)
//   bit  15   : level barrier (before zh)
// Fetch-bound theory (R0-R9 fit: time ~ 0.75us/KB of unrolled code per CU):
// rolled body ~2-3 KB is L1I-resident; R9's regression was per-node GLOBAL
// table loads on the critical path — here descriptors live in LDS, one
// broadcast ds_read_b32 per node, prefetched one iteration ahead, and
// readfirstlane'd to SGPRs for scalar branches/field extracts.
struct CWords { unsigned w[64]; };
constexpr CWords make_cwords() {
    CWords C{};
    for (int i = 0; i < 64; ++i) C.w[i] = 0;
    for (int g = 0; g < 32; ++g) {
        const int cB = PL3.gbeg[g], cE = PL3.gbeg[g + 1];
        for (int ci = cB; ci < cE; ++ci) {
            const unsigned jo = (unsigned)PL3.ch[ci].jo;
            const unsigned sl = PL3.ch[ci].sl < 0 ? 31u : (unsigned)PL3.ch[ci].sl;
            const unsigned rb = PL3.ch[ci].bar ? 1u : 0u;
            const unsigned ng = (ci == cB) ? 1u : 0u;
            const unsigned ps = PL3.gps[g] < 0 ? 31u : (unsigned)PL3.gps[g];
            C.w[ci] = jo | (sl << 3) | (rb << 8) | (ng << 9) | (ps << 10);
        }
    }
    for (int d = 1; d <= 6; ++d)
        C.w[PL3.gbeg[PL3.lvlG[d]]] |= (1u << 15);
    C.w[63] = 0;
    return C;
}
__device__ const CWords d_cw = make_cwords();

#define LOG2E   1.44269504f
#define TWOL2E  2.88539008f
#define SLOT_SH 2048            // shorts per slot (4 KB), h and c pools (pow2 -> shifts)

__device__ __forceinline__ unsigned short f2bf(float x) {
    union { float f; unsigned int u; } a; a.f = x;
    unsigned int r = (a.u + 0x7FFFu + ((a.u >> 16) & 1u)) >> 16;
    return (unsigned short)r;
}
__device__ __forceinline__ unsigned pk2(float a, float b) {
    union { __hip_bfloat162 h; unsigned u; } z;
    z.h = __float22bfloat162_rn(float2{a, b});
    return z.u;
}
__device__ __forceinline__ float bflo(unsigned p) {
    union { unsigned u; float f; } a; a.u = p << 16; return a.f;
}
__device__ __forceinline__ float bfhi(unsigned p) {
    union { unsigned u; float f; } a; a.u = p & 0xFFFF0000u; return a.f;
}

// h pool: hs[((slot*16 + kslot)*NSAMP + n)*8 + j]  (R0-verified layout)
// c pool: csb[t*4 + slot*2048]  lane-linear uint2  (R0-verified)

__global__ __launch_bounds__(BLOCK)
__attribute__((amdgpu_waves_per_eu(2, 4)))   // attested no-scratch envelope
void subset_lstm_skew_kernel(
    const float* __restrict__ x_input,
    const float* __restrict__ W_ih,
    const float* __restrict__ W_hh,
    const float* __restrict__ b_ih,
    const float* __restrict__ b_hh,
    const float* __restrict__ fc1_W,
    const float* __restrict__ fc1_b,
    const float* __restrict__ fc2_W,
    const float* __restrict__ fc2_b,
    float* __restrict__ out)
{
    __shared__ __align__(16) unsigned short hs [NSLOT * SLOT_SH];       // 56 KB
    __shared__ __align__(16) unsigned short csb[NSLOT * SLOT_SH];       // 56 KB
    __shared__ __align__(16) unsigned short xb[NOBJ * 4 * NSAMP * 8];   // 6 KB
    __shared__ unsigned cw_lds[64];                                     // 256 B
    float* s_maxh  = (float*)hs;                 // 8 KB  (post-LSTM alias)
    float* s_fc1   = (float*)(hs + 4096);        // 16 KB (post-LSTM alias)
    float* s_logit = (float*)xb;

    const int t      = threadIdx.x;
    const int w      = t >> 6;
    const int lane   = t & 63;
    const int quad   = lane >> 4;
    const int m16    = lane & 15;
    const int s_base = blockIdx.x * NSAMP;

    if (t < 64) cw_lds[t] = d_cw.w[t];

    // ---- x B-chunks: xb[obj][quad'][n][j]; quad2 j0 = 1.0 (bias lane), quad3 zero ----
    for (int idx = t; idx < NOBJ * 4 * NSAMP * 8; idx += BLOCK) {
        const int j = idx & 7, n = (idx >> 3) & 15, q = (idx >> 7) & 3, obj = idx >> 9;
        float v;
        if (q < 2) v = x_input[(s_base + n) * (NOBJ * DDIM) + obj * DDIM + q * 8 + j];
        else       v = (q == 2 && j == 0) ? 1.0f : 0.0f;
        xb[idx] = f2bf(v);
    }

    // ---- persistent A-frags wf[gate][chunk], PRE-SCALED (verified R8-R13) ----
    bf16x8 wf[4][5];
    #pragma unroll
    for (int g = 0; g < 4; ++g) {
        const float sc = (g == 2) ? TWOL2E : -LOG2E;
        const int grow = g * HDIM + w * 16 + m16;
        const float* whr = W_hh + grow * HDIM;
        const float* wir = W_ih + grow * DDIM;
        #pragma unroll
        for (int q = 0; q < 4; ++q) {
            union { unsigned short u[8]; bf16x8 v; } pk;
            #pragma unroll
            for (int j = 0; j < 8; ++j)
                pk.u[j] = f2bf(sc * whr[q * 32 + quad * 8 + j]);
            wf[g][q] = pk.v;
        }
        {
            union { unsigned short u[8]; bf16x8 v; } pk;
            #pragma unroll
            for (int j = 0; j < 8; ++j) {
                float v = 0.0f;
                if (quad < 2) v = sc * wir[quad * 8 + j];
                else if (quad == 2 && j == 0) v = sc * (b_ih[grow] + b_hh[grow]);
                pk.u[j] = f2bf(v);
            }
            wf[g][4] = pk.v;
        }
    }

    __syncthreads();    // xb + cw_lds visible

    float mh[4] = {-1e30f, -1e30f, -1e30f, -1e30f};
    const int kslot = w * 2 + (quad >> 1);
    unsigned short* const c_lane = &csb[t * 4];
    unsigned short* const h_rd   = &hs[quad * (NSAMP * 8) + m16 * 8];      // + ps*2048 + q*512
    unsigned short* const h_wr   = &hs[kslot * (NSAMP * 8) + m16 * 8 + (quad & 1) * 4];

    f32x4 zh[4];
    float cp4[4];
    #pragma unroll
    for (int g2 = 0; g2 < 4; ++g2) zh[g2] = f32x4{0.f, 0.f, 0.f, 0.f};
    #pragma unroll
    for (int r = 0; r < 4; ++r) cp4[r] = 0.0f;

    unsigned cw = __builtin_amdgcn_readfirstlane(cw_lds[0]);

    // ---- main loop: ROLLED flat over 63 children; desc prefetched 1 ahead ----
    #pragma unroll 1
    for (int ci = 0; ci < 63; ++ci) {
        const unsigned cw_n = cw_lds[ci + 1];     // broadcast read, latency hidden
        if (cw & (1u << 15)) __syncthreads();     // level barrier (before zh)
        if (cw & (1u << 9)) {                     // new group: zh chain + cp4
            const int ps = (cw >> 10) & 31;
            #pragma unroll
            for (int g2 = 0; g2 < 4; ++g2) zh[g2] = f32x4{0.f, 0.f, 0.f, 0.f};
            if (ps != 31) {
                const uint2 cpk = *(const uint2*)(c_lane + (ps << 11));
                cp4[0] = bflo(cpk.x); cp4[1] = bfhi(cpk.x);
                cp4[2] = bflo(cpk.y); cp4[3] = bfhi(cpk.y);
                const unsigned short* hb = h_rd + (ps << 11);
                #pragma unroll
                for (int q = 0; q < 4; ++q) {
                    const bf16x8 bh = *(const bf16x8*)(hb + q * 512);
                    #pragma unroll
                    for (int g2 = 0; g2 < 4; ++g2)
                        zh[g2] = __builtin_amdgcn_mfma_f32_16x16x32_bf16(
                            wf[g2][q], bh, zh[g2], 0, 0, 0);
                }
            } else {
                #pragma unroll
                for (int r = 0; r < 4; ++r) cp4[r] = 0.0f;
            }
        }
        if (cw & (1u << 8)) __syncthreads();      // recycle barrier (after zh read)
        const int jo = cw & 7;
        const int sl = (cw >> 3) & 31;
        const bf16x8 bfx = *(const bf16x8*)&xb[((jo * 4 + quad) * NSAMP + m16) * 8];
        f32x4 acc[4];
        #pragma unroll
        for (int g2 = 0; g2 < 4; ++g2)
            acc[g2] = __builtin_amdgcn_mfma_f32_16x16x32_bf16(
                wf[g2][4], bfx, zh[g2], 0, 0, 0);
        float cn4[4], hn4[4];
        #pragma unroll
        for (int r = 0; r < 4; ++r) {
            const float u  = 1.0f + __builtin_amdgcn_exp2f(acc[0][r]);
            const float q  = 1.0f + __builtin_amdgcn_exp2f(acc[1][r]);
            const float v  = 1.0f + __builtin_amdgcn_exp2f(acc[2][r]);
            const float qo = 1.0f + __builtin_amdgcn_exp2f(acc[3][r]);
            const float uv  = u * v;
            const float num = fmaf(q, v - 2.0f, cp4[r] * uv);
            const float cn  = num * __builtin_amdgcn_rcpf(q * uv);
            const float wt  = 1.0f + __builtin_amdgcn_exp2f(TWOL2E * cn);
            const float h   = (wt - 2.0f) * __builtin_amdgcn_rcpf(qo * wt);
            cn4[r] = cn; hn4[r] = h;
            mh[r] = fmaxf(mh[r], h);
        }
        if (sl != 31) {
            uint2 cw2; cw2.x = pk2(cn4[0], cn4[1]); cw2.y = pk2(cn4[2], cn4[3]);
            *(uint2*)(c_lane + (sl << 11)) = cw2;
            uint2 hw; hw.x = pk2(hn4[0], hn4[1]); hw.y = pk2(hn4[2], hn4[3]);
            *(uint2*)(h_wr + (sl << 11)) = hw;
        }
        cw = __builtin_amdgcn_readfirstlane(cw_n);
    }

    __syncthreads();   // pools dead; reuse hs for epilogue
    {
        float4 v; v.x = mh[0]; v.y = mh[1]; v.z = mh[2]; v.w = mh[3];
        *(float4*)&s_maxh[m16 * HDIM + w * 16 + quad * 4] = v;
    }
    __syncthreads();

    // ---- FC1: f = t&255, sample half t>>8 (8 samples each) ----
    {
        const int f  = t & 255;
        const int sh = t >> 8;
        float a1[8];
        #pragma unroll
        for (int s = 0; s < 8; ++s) a1[s] = fc1_b[f];
        for (int k4 = 0; k4 < HDIM / 4; ++k4) {
            const float4 wv = *(const float4*)&fc1_W[f * HDIM + k4 * 4];
            #pragma unroll
            for (int s = 0; s < 8; ++s) {
                const float4 h4 = *(const float4*)&s_maxh[(sh * 8 + s) * HDIM + k4 * 4];
                a1[s] += wv.x * h4.x + wv.y * h4.y + wv.z * h4.z + wv.w * h4.w;
            }
        }
        #pragma unroll
        for (int s = 0; s < 8; ++s)
            s_fc1[(sh * 8 + s) * 256 + f] = fmaxf(a1[s], 0.0f);
    }
    __syncthreads();

    if (t < NSAMP * 10) {
        const int s = t / 10, a = t % 10;
        float acc2 = fc2_b[a];
        for (int f4 = 0; f4 < 256 / 4; ++f4) {
            const float4 wv = *(const float4*)&fc2_W[a * 256 + f4 * 4];
            const float4 v  = *(const float4*)&s_fc1[s * 256 + f4 * 4];
            acc2 += wv.x * v.x + wv.y * v.y + wv.z * v.z + wv.w * v.w;
        }
        s_logit[s * 10 + a] = acc2;
    }
    __syncthreads();

    if (t < NSAMP) {
        float m = -1e30f;
        #pragma unroll
        for (int a = 0; a < 10; ++a) m = fmaxf(m, s_logit[t * 10 + a]);
        float sum = 0.0f;
        #pragma unroll
        for (int a = 0; a < 10; ++a) sum += __expf(s_logit[t * 10 + a] - m);
        const float lse = m + __logf(sum);
        #pragma unroll
        for (int a = 0; a < 10; ++a)
            out[(s_base + t) * 10 + a] = s_logit[t * 10 + a] - lse;
    }
}

extern "C" void kernel_launch(void* const* d_in, const int* in_sizes, int n_in,
                              void* d_out, int out_size, void* d_ws, size_t ws_size,
                              hipStream_t stream)
{
    (void)d_ws; (void)ws_size; (void)n_in; (void)out_size;

    const float* x   = (const float*)d_in[0];
    const float* Wih = (const float*)d_in[1];
    const float* Whh = (const float*)d_in[2];
    const float* bih = (const float*)d_in[3];
    const float* bhh = (const float*)d_in[4];
    const float* f1w = (const float*)d_in[5];
    const float* f1b = (const float*)d_in[6];
    const float* f2w = (const float*)d_in[7];
    const float* f2b = (const float*)d_in[8];

    const int mb = in_sizes[0] / (NOBJ * DDIM);   // 8192
    dim3 grid(mb / NSAMP), block(BLOCK);
    subset_lstm_skew_kernel<<<grid, block, 0, stream>>>(
        x, Wih, Whh, bih, bhh, f1w, f1b, f2w, f2b, (float*)d_out);
}

// Round 11
// 191.020 us; speedup vs baseline: 1.1640x; 1.1124x over previous
//
#include <hip/hip_runtime.h>
#include <hip/hip_bf16.h>

#define BLOCK   512     // 8 waves; wave w owns channels w*16..w*16+15, all 4 gates
#define NSAMP   16
#define HDIM    128
#define DDIM    16
#define NOBJ    6
#define NSLOT   20      // peak live slots of grouped plan = C(5,2)+C(5,3) = 20
                        //   -> ZERO recycle barriers (statically asserted)

typedef __attribute__((ext_vector_type(8))) short bf16x8;
typedef __attribute__((ext_vector_type(4))) float f32x4;

constexpr int pc6(int m)  { int c = 0; for (int i = 0; i < 6; ++i) c += (m >> i) & 1; return c; }
constexpr int msb6(int m) { int b = -1; for (int i = 0; i < 6; ++i) if (m & (1 << i)) b = i; return b; }

// ---- Grouped plan (verified R4): children grouped by PARENT so W_hh*h_P (zh)
// is computed ONCE per parent; slot pool with (now unused) recycle machinery.
struct GChild { int jo, sl; bool bar; };
struct Plan3 {
    int    gps [32];
    int    gbeg[33];
    GChild ch  [63];
    int    lvlG[8];
    bool   ok;
};
constexpr Plan3 make_plan3() {
    Plan3 P{};
    P.ok = true;
    int  slotOf[64] = {};
    bool busy[NSLOT] = {};
    int  pendingFree[NSLOT] = {};
    int  npend = 0;
    int  g = 0, cidx = 0;
    for (int d = 1; d <= 6; ++d) {
        P.lvlG[d] = g;
        for (int Pm = 0; Pm < 64; ++Pm) {
            if (pc6(Pm) != d - 1) continue;
            if (Pm != 0 && msb6(Pm) == 5) continue;
            P.gps[g]  = (Pm == 0) ? -1 : slotOf[Pm];
            P.gbeg[g] = cidx;
            if (Pm != 0) pendingFree[npend++] = slotOf[Pm];
            const int j0 = (Pm == 0) ? 0 : msb6(Pm) + 1;
            for (int j = j0; j <= 5; ++j) {
                const int M = Pm | (1 << j);
                P.ch[cidx].jo  = j;
                P.ch[cidx].bar = false;
                int sl = -1;
                if (j < 5) {
                    int fs = -1;
                    for (int s = 0; s < NSLOT; ++s) if (!busy[s]) { fs = s; break; }
                    if (fs < 0) {
                        P.ch[cidx].bar = true;
                        if (npend == 0) P.ok = false;
                        for (int i = 0; i < npend; ++i) busy[pendingFree[i]] = false;
                        npend = 0;
                        for (int s = 0; s < NSLOT; ++s) if (!busy[s]) { fs = s; break; }
                        if (fs < 0) P.ok = false;
                    }
                    if (fs >= 0) { busy[fs] = true; slotOf[M] = fs; sl = fs; }
                }
                P.ch[cidx].sl = sl;
                ++cidx;
            }
            ++g;
        }
        for (int i = 0; i < npend; ++i) busy[pendingFree[i]] = false;
        npend = 0;
    }
    P.lvlG[7] = g;
    P.gbeg[g] = cidx;
    if (g != 32 || cidx != 63) P.ok = false;
    return P;
}
constexpr Plan3 PL3 = make_plan3();
static_assert(PL3.ok, "plan allocation failed");
static_assert(PL3.lvlG[7] == 32, "32 groups expected");
static_assert(PL3.gbeg[32] == 63, "63 children expected");
constexpr int count_bars() {
    int n = 0;
    for (int i = 0; i < 63; ++i) if (PL3.ch[i].bar) ++n;
    return n;
}
static_assert(count_bars() == 0, "NSLOT=20 must eliminate all recycle barriers");

#define LOG2E   1.44269504f
#define TWOL2E  2.88539008f
#define SLOT_SH 2048            // shorts per slot (4 KB), h pool

__device__ __forceinline__ unsigned short f2bf(float x) {
    union { float f; unsigned int u; } a; a.f = x;
    unsigned int r = (a.u + 0x7FFFu + ((a.u >> 16) & 1u)) >> 16;
    return (unsigned short)r;
}
__device__ __forceinline__ unsigned pk2(float a, float b) {
    union { __hip_bfloat162 h; unsigned u; } z;
    z.h = __float22bfloat162_rn(float2{a, b});
    return z.u;
}
__device__ __forceinline__ float bflo(unsigned p) {
    union { unsigned u; float f; } a; a.u = p << 16; return a.f;
}
__device__ __forceinline__ float bfhi(unsigned p) {
    union { unsigned u; float f; } a; a.u = p & 0xFFFF0000u; return a.f;
}

// h pool: hs[((slot*16 + kslot)*NSAMP + n)*8 + j]  (R0-verified layout)
// c state: bf16-packed uint2 c_pk[20], lane-private, statically indexed
//   (R0/R8-verified precision; 40 regs vs R7's 56-f32 -> more spill margin).
// Leaf B-frag (jo=5, 32/63 children) hoisted to registers (8 VGPRs) —
//   removes a dependent ds_read from half the children's critical path.
// Structural floor model (R0-R10): weights-in-regs (80 VGPR) locks the CU at
//   2 barrier-locked waves/SIMD; occupancy (R1-R3), ILP (R8), code-size (R9/
//   R10), MFMA count (R6), trans count (R6) all individually falsified as
//   levers.  This round strips the residual barrier/ds serialization.

__global__ __launch_bounds__(BLOCK)
__attribute__((amdgpu_waves_per_eu(2, 4)))   // attested no-scratch envelope
void subset_lstm_skew_kernel(
    const float* __restrict__ x_input,
    const float* __restrict__ W_ih,
    const float* __restrict__ W_hh,
    const float* __restrict__ b_ih,
    const float* __restrict__ b_hh,
    const float* __restrict__ fc1_W,
    const float* __restrict__ fc1_b,
    const float* __restrict__ fc2_W,
    const float* __restrict__ fc2_b,
    float* __restrict__ out)
{
    __shared__ __align__(16) unsigned short hs [NSLOT * SLOT_SH];       // 80 KB
    __shared__ __align__(16) unsigned short xb[NOBJ * 4 * NSAMP * 8];   // 6 KB
    float* s_maxh  = (float*)hs;                 // 8 KB  (post-LSTM alias)
    float* s_fc1   = (float*)(hs + 4096);        // 16 KB (post-LSTM alias)
    float* s_logit = (float*)xb;

    const int t      = threadIdx.x;
    const int w      = t >> 6;
    const int lane   = t & 63;
    const int quad   = lane >> 4;
    const int m16    = lane & 15;
    const int s_base = blockIdx.x * NSAMP;

    // ---- x B-chunks: xb[obj][quad'][n][j]; quad2 j0 = 1.0 (bias lane), quad3 zero ----
    for (int idx = t; idx < NOBJ * 4 * NSAMP * 8; idx += BLOCK) {
        const int j = idx & 7, n = (idx >> 3) & 15, q = (idx >> 7) & 3, obj = idx >> 9;
        float v;
        if (q < 2) v = x_input[(s_base + n) * (NOBJ * DDIM) + obj * DDIM + q * 8 + j];
        else       v = (q == 2 && j == 0) ? 1.0f : 0.0f;
        xb[idx] = f2bf(v);
    }

    // ---- persistent A-frags wf[gate][chunk], PRE-SCALED (verified R8-R13) ----
    bf16x8 wf[4][5];
    #pragma unroll
    for (int g = 0; g < 4; ++g) {
        const float sc = (g == 2) ? TWOL2E : -LOG2E;
        const int grow = g * HDIM + w * 16 + m16;
        const float* whr = W_hh + grow * HDIM;
        const float* wir = W_ih + grow * DDIM;
        #pragma unroll
        for (int q = 0; q < 4; ++q) {
            union { unsigned short u[8]; bf16x8 v; } pk;
            #pragma unroll
            for (int j = 0; j < 8; ++j)
                pk.u[j] = f2bf(sc * whr[q * 32 + quad * 8 + j]);
            wf[g][q] = pk.v;
        }
        {
            union { unsigned short u[8]; bf16x8 v; } pk;
            #pragma unroll
            for (int j = 0; j < 8; ++j) {
                float v = 0.0f;
                if (quad < 2) v = sc * wir[quad * 8 + j];
                else if (quad == 2 && j == 0) v = sc * (b_ih[grow] + b_hh[grow]);
                pk.u[j] = f2bf(v);
            }
            wf[g][4] = pk.v;
        }
    }

    __syncthreads();    // xb visible; hoist the leaf (jo=5) B-frag to registers
    const bf16x8 bfx5 = *(const bf16x8*)&xb[((5 * 4 + quad) * NSAMP + m16) * 8];

    float mh[4] = {-1e30f, -1e30f, -1e30f, -1e30f};
    const int kslot = w * 2 + (quad >> 1);
    uint2 c_pk[NSLOT];      // bf16-packed c, lane-private, static idx

    // shared pointwise tail (verified R9-R13 math); c packed bf16
    auto pw_tail = [&](const f32x4 (&acc)[4], const float (&cp4)[4], int sl) {
        float cn4[4], hn4[4];
        #pragma unroll
        for (int r = 0; r < 4; ++r) {
            const float u  = 1.0f + __builtin_amdgcn_exp2f(acc[0][r]);
            const float q  = 1.0f + __builtin_amdgcn_exp2f(acc[1][r]);
            const float v  = 1.0f + __builtin_amdgcn_exp2f(acc[2][r]);
            const float qo = 1.0f + __builtin_amdgcn_exp2f(acc[3][r]);
            const float uv  = u * v;
            const float num = fmaf(q, v - 2.0f, cp4[r] * uv);
            const float cn  = num * __builtin_amdgcn_rcpf(q * uv);
            const float wt  = 1.0f + __builtin_amdgcn_exp2f(TWOL2E * cn);
            const float h   = (wt - 2.0f) * __builtin_amdgcn_rcpf(qo * wt);
            cn4[r] = cn; hn4[r] = h;
            mh[r] = fmaxf(mh[r], h);
        }
        if (sl >= 0) {
            c_pk[sl].x = pk2(cn4[0], cn4[1]);
            c_pk[sl].y = pk2(cn4[2], cn4[3]);
            uint2 hw; hw.x = pk2(hn4[0], hn4[1]); hw.y = pk2(hn4[2], hn4[3]);
            *(uint2*)&hs[((sl * 16 + kslot) * NSAMP + m16) * 8 + (quad & 1) * 4] = hw;
        }
    };

    // ---- main loop: per level, per parent-group (fully unrolled) ----
    #pragma unroll
    for (int d = 1; d <= 6; ++d) {
        __syncthreads();    // the ONLY barriers: 6 level barriers
        const int gBeg = PL3.lvlG[d];
        const int gEnd = PL3.lvlG[d + 1];
        #pragma unroll
        for (int gi = gBeg; gi < gEnd; ++gi) {
            const int ps = PL3.gps[gi];
            f32x4 zh[4];
            float cp4[4];
            #pragma unroll
            for (int g2 = 0; g2 < 4; ++g2) zh[g2] = f32x4{0.f, 0.f, 0.f, 0.f};
            if (ps >= 0) {
                cp4[0] = bflo(c_pk[ps].x); cp4[1] = bfhi(c_pk[ps].x);
                cp4[2] = bflo(c_pk[ps].y); cp4[3] = bfhi(c_pk[ps].y);
                #pragma unroll
                for (int q = 0; q < 4; ++q) {
                    const bf16x8 bh = *(const bf16x8*)
                        &hs[((ps * 16 + q * 4 + quad) * NSAMP + m16) * 8];
                    #pragma unroll
                    for (int g2 = 0; g2 < 4; ++g2)
                        zh[g2] = __builtin_amdgcn_mfma_f32_16x16x32_bf16(
                            wf[g2][q], bh, zh[g2], 0, 0, 0);
                }
            } else {
                #pragma unroll
                for (int r = 0; r < 4; ++r) cp4[r] = 0.0f;
            }
            // -- children: x-MFMA with C=zh, then pointwise --
            #pragma unroll
            for (int ci = PL3.gbeg[gi]; ci < PL3.gbeg[gi + 1]; ++ci) {
                const int jo = PL3.ch[ci].jo;
                const bf16x8 bfx = (jo == 5) ? bfx5 :
                    *(const bf16x8*)&xb[((jo * 4 + quad) * NSAMP + m16) * 8];
                f32x4 acc[4];
                #pragma unroll
                for (int g2 = 0; g2 < 4; ++g2)
                    acc[g2] = __builtin_amdgcn_mfma_f32_16x16x32_bf16(
                        wf[g2][4], bfx, zh[g2], 0, 0, 0);
                pw_tail(acc, cp4, PL3.ch[ci].sl);
            }
        }
    }

    __syncthreads();   // pools dead; reuse hs for epilogue
    {
        float4 v; v.x = mh[0]; v.y = mh[1]; v.z = mh[2]; v.w = mh[3];
        *(float4*)&s_maxh[m16 * HDIM + w * 16 + quad * 4] = v;
    }
    __syncthreads();

    // ---- FC1: f = t&255, sample half t>>8 (8 samples each) ----
    {
        const int f  = t & 255;
        const int sh = t >> 8;
        float a1[8];
        #pragma unroll
        for (int s = 0; s < 8; ++s) a1[s] = fc1_b[f];
        for (int k4 = 0; k4 < HDIM / 4; ++k4) {
            const float4 wv = *(const float4*)&fc1_W[f * HDIM + k4 * 4];
            #pragma unroll
            for (int s = 0; s < 8; ++s) {
                const float4 h4 = *(const float4*)&s_maxh[(sh * 8 + s) * HDIM + k4 * 4];
                a1[s] += wv.x * h4.x + wv.y * h4.y + wv.z * h4.z + wv.w * h4.w;
            }
        }
        #pragma unroll
        for (int s = 0; s < 8; ++s)
            s_fc1[(sh * 8 + s) * 256 + f] = fmaxf(a1[s], 0.0f);
    }
    __syncthreads();

    if (t < NSAMP * 10) {
        const int s = t / 10, a = t % 10;
        float acc2 = fc2_b[a];
        for (int f4 = 0; f4 < 256 / 4; ++f4) {
            const float4 wv = *(const float4*)&fc2_W[a * 256 + f4 * 4];
            const float4 v  = *(const float4*)&s_fc1[s * 256 + f4 * 4];
            acc2 += wv.x * v.x + wv.y * v.y + wv.z * v.z + wv.w * v.w;
        }
        s_logit[s * 10 + a] = acc2;
    }
    __syncthreads();

    if (t < NSAMP) {
        float m = -1e30f;
        #pragma unroll
        for (int a = 0; a < 10; ++a) m = fmaxf(m, s_logit[t * 10 + a]);
        float sum = 0.0f;
        #pragma unroll
        for (int a = 0; a < 10; ++a) sum += __expf(s_logit[t * 10 + a] - m);
        const float lse = m + __logf(sum);
        #pragma unroll
        for (int a = 0; a < 10; ++a)
            out[(s_base + t) * 10 + a] = s_logit[t * 10 + a] - lse;
    }
}

extern "C" void kernel_launch(void* const* d_in, const int* in_sizes, int n_in,
                              void* d_out, int out_size, void* d_ws, size_t ws_size,
                              hipStream_t stream)
{
    (void)d_ws; (void)ws_size; (void)n_in; (void)out_size;

    const float* x   = (const float*)d_in[0];
    const float* Wih = (const float*)d_in[1];
    const float* Whh = (const float*)d_in[2];
    const float* bih = (const float*)d_in[3];
    const float* bhh = (const float*)d_in[4];
    const float* f1w = (const float*)d_in[5];
    const float* f1b = (const float*)d_in[6];
    const float* f2w = (const float*)d_in[7];
    const float* f2b = (const float*)d_in[8];

    const int mb = in_sizes[0] / (NOBJ * DDIM);   // 8192
    dim3 grid(mb / NSAMP), block(BLOCK);
    subset_lstm_skew_kernel<<<grid, block, 0, stream>>>(
        x, Wih, Whh, bih, bhh, f1w, f1b, f2w, f2b, (float*)d_out);
}

// Round 12
// 187.875 us; speedup vs baseline: 1.1835x; 1.0167x over previous
//
#include <hip/hip_runtime.h>
#include <hip/hip_bf16.h>

#define BLOCK   512     // 8 waves; wave w owns channels w*16..w*16+15, all 4 gates
#define NSAMP   16
#define HDIM    128
#define DDIM    16
#define NOBJ    6
#define NSLOT   14

typedef __attribute__((ext_vector_type(8))) short bf16x8;
typedef __attribute__((ext_vector_type(4))) float f32x4;

constexpr int pc6(int m)  { int c = 0; for (int i = 0; i < 6; ++i) c += (m >> i) & 1; return c; }
constexpr int msb6(int m) { int b = -1; for (int i = 0; i < 6; ++i) if (m & (1 << i)) b = i; return b; }

// ---- Grouped plan (verified R4): children grouped by PARENT so W_hh*h_P (zh)
// is computed ONCE per parent. Parent slot freeable once zh/c read (cached in
// regs); allocator inserts recycle barriers when the 14-slot pool is full.
struct GChild { int jo, sl; bool bar; };
struct Plan3 {
    int    gps [32];    // parent slot per group (-1 for the root pseudo-parent)
    int    gbeg[33];    // child range per group: [gbeg[g], gbeg[g+1])
    GChild ch  [63];
    int    lvlG[8];     // group range per level d: [lvlG[d], lvlG[d+1])
    bool   ok;
};
constexpr Plan3 make_plan3() {
    Plan3 P{};
    P.ok = true;
    int  slotOf[64] = {};
    bool busy[NSLOT] = {};
    int  pendingFree[NSLOT] = {};   // parent slots read, freeable at next barrier
    int  npend = 0;
    int  g = 0, cidx = 0;
    for (int d = 1; d <= 6; ++d) {
        P.lvlG[d] = g;
        for (int Pm = 0; Pm < 64; ++Pm) {
            if (pc6(Pm) != d - 1) continue;
            if (Pm != 0 && msb6(Pm) == 5) continue;      // leaves have no children
            P.gps[g]  = (Pm == 0) ? -1 : slotOf[Pm];
            P.gbeg[g] = cidx;
            if (Pm != 0) pendingFree[npend++] = slotOf[Pm];   // zh/c read at group start
            const int j0 = (Pm == 0) ? 0 : msb6(Pm) + 1;
            for (int j = j0; j <= 5; ++j) {
                const int M = Pm | (1 << j);
                P.ch[cidx].jo  = j;
                P.ch[cidx].bar = false;
                int sl = -1;
                if (j < 5) {
                    int fs = -1;
                    for (int s = 0; s < NSLOT; ++s) if (!busy[s]) { fs = s; break; }
                    if (fs < 0) {   // recycle barrier: free all pending parents
                        P.ch[cidx].bar = true;
                        if (npend == 0) P.ok = false;
                        for (int i = 0; i < npend; ++i) busy[pendingFree[i]] = false;
                        npend = 0;
                        for (int s = 0; s < NSLOT; ++s) if (!busy[s]) { fs = s; break; }
                        if (fs < 0) P.ok = false;
                    }
                    if (fs >= 0) { busy[fs] = true; slotOf[M] = fs; sl = fs; }
                }
                P.ch[cidx].sl = sl;
                ++cidx;
            }
            ++g;
        }
        // level-end barrier frees all parents read during this level
        for (int i = 0; i < npend; ++i) busy[pendingFree[i]] = false;
        npend = 0;
    }
    P.lvlG[7] = g;
    P.gbeg[g] = cidx;
    if (g != 32 || cidx != 63) P.ok = false;
    return P;
}
constexpr Plan3 PL3 = make_plan3();
static_assert(PL3.ok, "plan allocation failed");
static_assert(PL3.lvlG[7] == 32, "32 groups expected");
static_assert(PL3.gbeg[32] == 63, "63 children expected");

#define LOG2E   1.44269504f
#define TWOL2E  2.88539008f
#define SLOT_SH 2048            // shorts per slot (4 KB), h pool

__device__ __forceinline__ unsigned short f2bf(float x) {
    union { float f; unsigned int u; } a; a.f = x;
    unsigned int r = (a.u + 0x7FFFu + ((a.u >> 16) & 1u)) >> 16;
    return (unsigned short)r;
}
__device__ __forceinline__ unsigned pk2(float a, float b) {
    union { __hip_bfloat162 h; unsigned u; } z;
    z.h = __float22bfloat162_rn(float2{a, b});
    return z.u;
}

// h pool: hs[((slot*16 + kslot)*NSAMP + n)*8 + j] = h[ch = kslot*8+j][sample n]
//   B-frag chunk q, lane (quad,m16): kslot = q*4+quad -> 16B-aligned ds_read_b128
//   wave w writes ch = w*16+quad*4+r at kslot = w*2+(quad>>1), j = (quad&1)*4+r
// c state: f32 in registers c_slots[NSLOT][4], statically indexed (R6/R7-
//   verified: VGPR_Count=108, zero scratch).
// Final structural model (R0-R11): weight-resident MFMA design (80 VGPR/lane)
//   caps the CU at 2 barrier-locked waves/SIMD (total RF/wave ~176 > 128);
//   at that occupancy the kernel sits at a latency floor of ~135 us that is
//   invariant to MFMA count (R6), trans count (R6), ILP (R8), barriers (R11),
//   pipelining (R5), and code size (R9/R10).  Moving weights out of registers
//   (R1-R3) costs 2.3-2.7x in scratch traffic.  This is the attested-best
//   configuration (R7: 135.5 us dispatch / 187.35 us bench).

__global__ __launch_bounds__(BLOCK)
__attribute__((amdgpu_waves_per_eu(2, 4)))   // only attested no-spill envelope
void subset_lstm_skew_kernel(
    const float* __restrict__ x_input,
    const float* __restrict__ W_ih,
    const float* __restrict__ W_hh,
    const float* __restrict__ b_ih,
    const float* __restrict__ b_hh,
    const float* __restrict__ fc1_W,
    const float* __restrict__ fc1_b,
    const float* __restrict__ fc2_W,
    const float* __restrict__ fc2_b,
    float* __restrict__ out)
{
    __shared__ __align__(16) unsigned short hs [NSLOT * SLOT_SH];       // 56 KB
    __shared__ __align__(16) unsigned short xb[NOBJ * 4 * NSAMP * 8];   // 6 KB
    float* s_maxh  = (float*)hs;                 // 8 KB  (post-LSTM alias)
    float* s_fc1   = (float*)(hs + 4096);        // 16 KB (post-LSTM alias)
    float* s_logit = (float*)xb;

    const int t      = threadIdx.x;
    const int w      = t >> 6;
    const int lane   = t & 63;
    const int quad   = lane >> 4;
    const int m16    = lane & 15;
    const int s_base = blockIdx.x * NSAMP;

    // ---- x B-chunks: xb[obj][quad'][n][j]; quad2 j0 = 1.0 (bias lane), quad3 zero ----
    for (int idx = t; idx < NOBJ * 4 * NSAMP * 8; idx += BLOCK) {
        const int j = idx & 7, n = (idx >> 3) & 15, q = (idx >> 7) & 3, obj = idx >> 9;
        float v;
        if (q < 2) v = x_input[(s_base + n) * (NOBJ * DDIM) + obj * DDIM + q * 8 + j];
        else       v = (q == 2 && j == 0) ? 1.0f : 0.0f;
        xb[idx] = f2bf(v);
    }

    // ---- persistent A-frags wf[gate][chunk], PRE-SCALED (verified R8-R13) ----
    bf16x8 wf[4][5];
    #pragma unroll
    for (int g = 0; g < 4; ++g) {
        const float sc = (g == 2) ? TWOL2E : -LOG2E;
        const int grow = g * HDIM + w * 16 + m16;
        const float* whr = W_hh + grow * HDIM;
        const float* wir = W_ih + grow * DDIM;
        #pragma unroll
        for (int q = 0; q < 4; ++q) {
            union { unsigned short u[8]; bf16x8 v; } pk;
            #pragma unroll
            for (int j = 0; j < 8; ++j)
                pk.u[j] = f2bf(sc * whr[q * 32 + quad * 8 + j]);
            wf[g][q] = pk.v;
        }
        {
            union { unsigned short u[8]; bf16x8 v; } pk;
            #pragma unroll
            for (int j = 0; j < 8; ++j) {
                float v = 0.0f;
                if (quad < 2) v = sc * wir[quad * 8 + j];
                else if (quad == 2 && j == 0) v = sc * (b_ih[grow] + b_hh[grow]);
                pk.u[j] = f2bf(v);
            }
            wf[g][4] = pk.v;
        }
    }

    float mh[4] = {-1e30f, -1e30f, -1e30f, -1e30f};
    const int kslot = w * 2 + (quad >> 1);
    float c_slots[NSLOT][4];    // f32 c state, lane-private, static idx

    // shared pointwise tail: (u,q,v,qo,cprev) -> cn,h ; publish if sl>=0
    auto pw_tail = [&](const float (&u4)[4], const float (&q4)[4],
                       const float (&v4)[4], const float (&qo4)[4],
                       const float (&cp4)[4], int sl) {
        float hn4[4];
        #pragma unroll
        for (int r = 0; r < 4; ++r) {
            const float uv  = u4[r] * v4[r];
            const float num = fmaf(q4[r], v4[r] - 2.0f, cp4[r] * uv);
            const float cn  = num * __builtin_amdgcn_rcpf(q4[r] * uv);
            const float wt  = 1.0f + __builtin_amdgcn_exp2f(TWOL2E * cn);
            const float h   = (wt - 2.0f) * __builtin_amdgcn_rcpf(qo4[r] * wt);
            hn4[r] = h;
            mh[r] = fmaxf(mh[r], h);
            if (sl >= 0) c_slots[sl][r] = cn;
        }
        if (sl >= 0) {
            uint2 hw; hw.x = pk2(hn4[0], hn4[1]); hw.y = pk2(hn4[2], hn4[3]);
            *(uint2*)&hs[((sl * 16 + kslot) * NSAMP + m16) * 8 + (quad & 1) * 4] = hw;
        }
    };

    // ---- main loop: per level, per parent-group ----
    #pragma unroll
    for (int d = 1; d <= 6; ++d) {
        __syncthreads();
        const int gBeg = PL3.lvlG[d];
        const int gEnd = PL3.lvlG[d + 1];
        #pragma unroll
        for (int gi = gBeg; gi < gEnd; ++gi) {
            const int ps = PL3.gps[gi];
            // -- zh chain (16 MFMA) + cprev (regs) --
            f32x4 zh[4];
            float cp4[4];
            #pragma unroll
            for (int g2 = 0; g2 < 4; ++g2) zh[g2] = f32x4{0.f, 0.f, 0.f, 0.f};
            if (ps >= 0) {
                #pragma unroll
                for (int q = 0; q < 4; ++q) {
                    const bf16x8 bh = *(const bf16x8*)
                        &hs[((ps * 16 + q * 4 + quad) * NSAMP + m16) * 8];
                    #pragma unroll
                    for (int g2 = 0; g2 < 4; ++g2)
                        zh[g2] = __builtin_amdgcn_mfma_f32_16x16x32_bf16(
                            wf[g2][q], bh, zh[g2], 0, 0, 0);
                }
                #pragma unroll
                for (int r = 0; r < 4; ++r) cp4[r] = c_slots[ps][r];
            } else {
                #pragma unroll
                for (int r = 0; r < 4; ++r) cp4[r] = 0.0f;
            }
            // -- children: x-MFMA with C=zh, then pointwise --
            #pragma unroll
            for (int ci = PL3.gbeg[gi]; ci < PL3.gbeg[gi + 1]; ++ci) {
                if (PL3.ch[ci].bar) __syncthreads();   // recycle barrier (constexpr)
                const int jo = PL3.ch[ci].jo;
                const bf16x8 bfx = *(const bf16x8*)
                    &xb[((jo * 4 + quad) * NSAMP + m16) * 8];
                f32x4 acc[4];
                #pragma unroll
                for (int g2 = 0; g2 < 4; ++g2)
                    acc[g2] = __builtin_amdgcn_mfma_f32_16x16x32_bf16(
                        wf[g2][4], bfx, zh[g2], 0, 0, 0);
                float u4[4], q4[4], v4[4], qo4[4];
                #pragma unroll
                for (int r = 0; r < 4; ++r) {
                    u4[r]  = 1.0f + __builtin_amdgcn_exp2f(acc[0][r]);
                    q4[r]  = 1.0f + __builtin_amdgcn_exp2f(acc[1][r]);
                    v4[r]  = 1.0f + __builtin_amdgcn_exp2f(acc[2][r]);
                    qo4[r] = 1.0f + __builtin_amdgcn_exp2f(acc[3][r]);
                }
                pw_tail(u4, q4, v4, qo4, cp4, PL3.ch[ci].sl);
            }
        }
    }

    __syncthreads();   // pools dead; reuse hs for epilogue
    {
        float4 v; v.x = mh[0]; v.y = mh[1]; v.z = mh[2]; v.w = mh[3];
        *(float4*)&s_maxh[m16 * HDIM + w * 16 + quad * 4] = v;
    }
    __syncthreads();

    // ---- FC1: f = t&255, sample half t>>8 (8 samples each) ----
    {
        const int f  = t & 255;
        const int sh = t >> 8;
        float a1[8];
        #pragma unroll
        for (int s = 0; s < 8; ++s) a1[s] = fc1_b[f];
        for (int k4 = 0; k4 < HDIM / 4; ++k4) {
            const float4 wv = *(const float4*)&fc1_W[f * HDIM + k4 * 4];
            #pragma unroll
            for (int s = 0; s < 8; ++s) {
                const float4 h4 = *(const float4*)&s_maxh[(sh * 8 + s) * HDIM + k4 * 4];
                a1[s] += wv.x * h4.x + wv.y * h4.y + wv.z * h4.z + wv.w * h4.w;
            }
        }
        #pragma unroll
        for (int s = 0; s < 8; ++s)
            s_fc1[(sh * 8 + s) * 256 + f] = fmaxf(a1[s], 0.0f);
    }
    __syncthreads();

    if (t < NSAMP * 10) {
        const int s = t / 10, a = t % 10;
        float acc2 = fc2_b[a];
        for (int f4 = 0; f4 < 256 / 4; ++f4) {
            const float4 wv = *(const float4*)&fc2_W[a * 256 + f4 * 4];
            const float4 v  = *(const float4*)&s_fc1[s * 256 + f4 * 4];
            acc2 += wv.x * v.x + wv.y * v.y + wv.z * v.z + wv.w * v.w;
        }
        s_logit[s * 10 + a] = acc2;
    }
    __syncthreads();

    if (t < NSAMP) {
        float m = -1e30f;
        #pragma unroll
        for (int a = 0; a < 10; ++a) m = fmaxf(m, s_logit[t * 10 + a]);
        float sum = 0.0f;
        #pragma unroll
        for (int a = 0; a < 10; ++a) sum += __expf(s_logit[t * 10 + a] - m);
        const float lse = m + __logf(sum);
        #pragma unroll
        for (int a = 0; a < 10; ++a)
            out[(s_base + t) * 10 + a] = s_logit[t * 10 + a] - lse;
    }
}

extern "C" void kernel_launch(void* const* d_in, const int* in_sizes, int n_in,
                              void* d_out, int out_size, void* d_ws, size_t ws_size,
                              hipStream_t stream)
{
    (void)d_ws; (void)ws_size; (void)n_in; (void)out_size;

    const float* x   = (const float*)d_in[0];
    const float* Wih = (const float*)d_in[1];
    const float* Whh = (const float*)d_in[2];
    const float* bih = (const float*)d_in[3];
    const float* bhh = (const float*)d_in[4];
    const float* f1w = (const float*)d_in[5];
    const float* f1b = (const float*)d_in[6];
    const float* f2w = (const float*)d_in[7];
    const float* f2b = (const float*)d_in[8];

    const int mb = in_sizes[0] / (NOBJ * DDIM);   // 8192
    dim3 grid(mb / NSAMP), block(BLOCK);
    subset_lstm_skew_kernel<<<grid, block, 0, stream>>>(
        x, Wih, Whh, bih, bhh, f1w, f1b, f2w, f2b, (float*)d_out);
}